// Round 16
// baseline (780.033 us; speedup 1.0000x reference)
//
#include <hip/hip_runtime.h>
#include <hip/hip_bf16.h>
#include <stdint.h>

#define SEQ 2048
#define DIMSZ 4096
#define QKVN 6144   // 4096 Q + 1024 K + 1024 V

typedef __attribute__((ext_vector_type(8))) __bf16 bf16x8;
typedef __attribute__((ext_vector_type(4))) float f32x4;

// async global->LDS, 16B per lane; dest = wave-uniform base + lane*16
static __device__ __forceinline__ void gld_lds16(const void* g, void* l) {
  __builtin_amdgcn_global_load_lds(
      (__attribute__((address_space(1))) void*)(g),
      (__attribute__((address_space(3))) void*)(l), 16, 0, 0);
}

// ---------------- merged fp32 -> bf16 conversion (one launch, 5 segments) --
__global__ __launch_bounds__(256) void k_cvt5(const float* __restrict__ x,
                                              const float* __restrict__ wq,
                                              const float* __restrict__ wk,
                                              const float* __restrict__ wv,
                                              const float* __restrict__ wo,
                                              __bf16* __restrict__ xb,
                                              __bf16* __restrict__ wqkvb,
                                              __bf16* __restrict__ wob) {
  long vid = (long)blockIdx.x * 256 + threadIdx.x;
  const long stride = (long)gridDim.x * 256;
  for (; vid < 7340032L; vid += stride) {
    const float* src; __bf16* dst; long off;
    if (vid < 2097152L)      { src = x;  dst = xb;                off = vid; }
    else if (vid < 4194304L) { src = wq; dst = wqkvb;             off = vid - 2097152L; }
    else if (vid < 4718592L) { src = wk; dst = wqkvb + 16777216L; off = vid - 4194304L; }
    else if (vid < 5242880L) { src = wv; dst = wqkvb + 20971520L; off = vid - 4718592L; }
    else                     { src = wo; dst = wob;               off = vid - 5242880L; }
    const long e = off * 8;
    float4 v0 = *(const float4*)(src + e);
    float4 v1 = *(const float4*)(src + e + 4);
    bf16x8 o;
    o[0] = (__bf16)v0.x; o[1] = (__bf16)v0.y; o[2] = (__bf16)v0.z; o[3] = (__bf16)v0.w;
    o[4] = (__bf16)v1.x; o[5] = (__bf16)v1.y; o[6] = (__bf16)v1.z; o[7] = (__bf16)v1.w;
    *(bf16x8*)(dst + e) = o;
  }
}

// ---------------- GEMM1: C = A*B^T, 128x256 tile, BK=64, triple-buffer -----
// r14 best (236 µs): grid (24,32) = 768 blocks = 3 exact rounds, zero tail.
// r15's 256x384/wave-128x96 variant REGRESSED (250 µs) -> wave-tile axis
// closed; this is the best measured GEMM1 structure.
__global__ __launch_bounds__(512) void k_gemm128x256(const __bf16* __restrict__ A,
                                                     const __bf16* __restrict__ B,
                                                     __bf16* __restrict__ C,
                                                     int M, int N, int K) {
  __shared__ __align__(16) __bf16 As[3][128 * 64];  // 48 KB
  __shared__ __align__(16) __bf16 Bs[3][256 * 64];  // 96 KB
  const int t = threadIdx.x;
  const int l = t & 63;
  const int w = t >> 6;        // 0..7
  const int wm = w >> 2;       // 0..1 : rows wm*64..+64
  const int wn = w & 3;        // 0..3 : cols wn*64..+64
  const int lr = l & 15, lg = l >> 4;
  const int sw = lr & 7;       // read-side chunk XOR
  const int bm = blockIdx.y, bn = blockIdx.x;

  const int srow = t >> 3;
  const int scol = ((t & 7) ^ (srow & 7)) << 3;
  const __bf16* pa0 = A + (size_t)(bm * 128 +   0 + srow) * K + scol;
  const __bf16* pa1 = A + (size_t)(bm * 128 +  64 + srow) * K + scol;
  const __bf16* pb0 = B + (size_t)(bn * 256 +   0 + srow) * K + scol;
  const __bf16* pb1 = B + (size_t)(bn * 256 +  64 + srow) * K + scol;
  const __bf16* pb2 = B + (size_t)(bn * 256 + 128 + srow) * K + scol;
  const __bf16* pb3 = B + (size_t)(bn * 256 + 192 + srow) * K + scol;
  const int ldst = t * 8;

#define SA(buf, kc) { gld_lds16(pa0 + (kc), &As[buf][ldst]);        \
                      gld_lds16(pa1 + (kc), &As[buf][4096 + ldst]); }
#define SB(buf, kc) { gld_lds16(pb0 + (kc), &Bs[buf][ldst]);        \
                      gld_lds16(pb1 + (kc), &Bs[buf][4096 + ldst]); \
                      gld_lds16(pb2 + (kc), &Bs[buf][8192 + ldst]); \
                      gld_lds16(pb3 + (kc), &Bs[buf][12288 + ldst]); }

  const int c0 = ((lg ^ sw) * 8);
  const int c1 = (((lg ^ sw) ^ 4) * 8);
  const int aBase = wm * 4096 + lr * 64;
  const int bBase = wn * 4096 + lr * 64;

#define PHTOP()                                        \
  asm volatile("" ::: "memory");                       \
  __builtin_amdgcn_s_barrier();                        \
  asm volatile("s_waitcnt lgkmcnt(0)" ::: "memory");   \
  __builtin_amdgcn_s_setprio(1)
#define PHEND()                                        \
  __builtin_amdgcn_s_setprio(0);                       \
  asm volatile("" ::: "memory");                       \
  __builtin_amdgcn_s_barrier()
#define PHENDW()                                       \
  __builtin_amdgcn_s_setprio(0);                       \
  asm volatile("s_waitcnt vmcnt(6)" ::: "memory");     \
  __builtin_amdgcn_s_barrier()

  f32x4 acc[4][4] = {};
  const int nt = K >> 6;

  SA(0, 0); SB(0, 0);
  SA(1, 64); SB(1, 64);
  asm volatile("s_waitcnt vmcnt(6)" ::: "memory");
  asm volatile("" ::: "memory");
  __builtin_amdgcn_s_barrier();
  asm volatile("" ::: "memory");

  int bu = 0, bu2 = 2;
  for (int U = 0; U < nt; ++U) {
    const int kc = (U + 2 < nt ? U + 2 : nt - 1) << 6;
    bf16x8 a[4][2], b[2][2];

    // ---- ph0: a(all) x b01; stage A(U+2) ----
#pragma unroll
    for (int mi = 0; mi < 4; ++mi) {
      a[mi][0] = *(const bf16x8*)&As[bu][aBase + mi * 1024 + c0];
      a[mi][1] = *(const bf16x8*)&As[bu][aBase + mi * 1024 + c1];
    }
#pragma unroll
    for (int ni = 0; ni < 2; ++ni) {
      b[ni][0] = *(const bf16x8*)&Bs[bu][bBase + ni * 1024 + c0];
      b[ni][1] = *(const bf16x8*)&Bs[bu][bBase + ni * 1024 + c1];
    }
    SA(bu2, kc);
    PHTOP();
#pragma unroll
    for (int mi = 0; mi < 4; ++mi)
#pragma unroll
      for (int ni = 0; ni < 2; ++ni)
#pragma unroll
        for (int kk = 0; kk < 2; ++kk)
          acc[mi][ni] = __builtin_amdgcn_mfma_f32_16x16x32_bf16(a[mi][kk], b[ni][kk], acc[mi][ni], 0, 0, 0);
    PHEND();

    // ---- ph1: a(all) x b23; stage B(U+2); counted vmcnt(6) ----
#pragma unroll
    for (int ni = 0; ni < 2; ++ni) {
      b[ni][0] = *(const bf16x8*)&Bs[bu][bBase + (ni + 2) * 1024 + c0];
      b[ni][1] = *(const bf16x8*)&Bs[bu][bBase + (ni + 2) * 1024 + c1];
    }
    SB(bu2, kc);
    PHTOP();
#pragma unroll
    for (int mi = 0; mi < 4; ++mi)
#pragma unroll
      for (int ni = 0; ni < 2; ++ni)
#pragma unroll
        for (int kk = 0; kk < 2; ++kk)
          acc[mi][ni + 2] = __builtin_amdgcn_mfma_f32_16x16x32_bf16(a[mi][kk], b[ni][kk], acc[mi][ni + 2], 0, 0, 0);
    PHENDW();

    bu = (bu == 2) ? 0 : bu + 1;
    bu2 = (bu2 == 2) ? 0 : bu2 + 1;
  }
#undef SA
#undef SB
#undef PHTOP
#undef PHEND
#undef PHENDW

  const int row0 = bm * 128 + wm * 64;
  const int col0 = bn * 256 + wn * 64;
#pragma unroll
  for (int mi = 0; mi < 4; ++mi)
#pragma unroll
    for (int ni = 0; ni < 4; ++ni)
#pragma unroll
      for (int r = 0; r < 4; ++r)
        C[(size_t)(row0 + mi * 16 + lg * 4 + r) * N + (col0 + ni * 16 + lr)] =
            (__bf16)acc[mi][ni][r];
}

// ---------------- GEMM2: r13 8-phase 256x256 kernel (unchanged, tail-free) -
template <typename OutT>
__global__ __launch_bounds__(512) void k_gemm8p(const __bf16* __restrict__ A,
                                                const __bf16* __restrict__ B,
                                                OutT* __restrict__ C,
                                                int M, int N, int K) {
  __shared__ __align__(16) __bf16 As[2][2][128 * 64];  // 64 KiB
  __shared__ __align__(16) __bf16 Bs[2][2][128 * 64];  // 64 KiB
  const int t = threadIdx.x;
  const int l = t & 63;
  const int w = t >> 6;
  const int wm = w >> 2;
  const int wn = w & 3;
  const int lr = l & 15, lg = l >> 4;
  const int sw = lr & 7;
  const int bm = blockIdx.y, bn = blockIdx.x;

  const int srow = t >> 3;
  const int scol = ((t & 7) ^ (srow & 7)) << 3;
  const __bf16* pa0 = A + (size_t)(bm * 256 +   0 + srow) * K + scol;
  const __bf16* pa1 = A + (size_t)(bm * 256 +  64 + srow) * K + scol;
  const __bf16* pa2 = A + (size_t)(bm * 256 + 128 + srow) * K + scol;
  const __bf16* pa3 = A + (size_t)(bm * 256 + 192 + srow) * K + scol;
  const __bf16* pb0 = B + (size_t)(bn * 256 +   0 + srow) * K + scol;
  const __bf16* pb1 = B + (size_t)(bn * 256 +  64 + srow) * K + scol;
  const __bf16* pb2 = B + (size_t)(bn * 256 + 128 + srow) * K + scol;
  const __bf16* pb3 = B + (size_t)(bn * 256 + 192 + srow) * K + scol;
  const int ldst = t * 8;

#define SA0(buf, kc) { gld_lds16(pa0 + (kc), &As[buf][0][ldst]); gld_lds16(pa1 + (kc), &As[buf][0][4096 + ldst]); }
#define SA1(buf, kc) { gld_lds16(pa2 + (kc), &As[buf][1][ldst]); gld_lds16(pa3 + (kc), &As[buf][1][4096 + ldst]); }
#define SB0(buf, kc) { gld_lds16(pb0 + (kc), &Bs[buf][0][ldst]); gld_lds16(pb1 + (kc), &Bs[buf][0][4096 + ldst]); }
#define SB1(buf, kc) { gld_lds16(pb2 + (kc), &Bs[buf][1][ldst]); gld_lds16(pb3 + (kc), &Bs[buf][1][4096 + ldst]); }

  const int c0 = ((lg ^ sw) * 8);
  const int c1 = (((lg ^ sw) ^ 4) * 8);
  const int aRow = lr;
  const int bRow = (wn & 1) * 64 + lr;

#define RDA(mi0, cur)                                                          \
  _Pragma("unroll") for (int mi = 0; mi < 4; ++mi) {                           \
    a[mi][0] = *(const bf16x8*)&As[cur][wm][(((mi0) + mi) * 16 + aRow) * 64 + c0]; \
    a[mi][1] = *(const bf16x8*)&As[cur][wm][(((mi0) + mi) * 16 + aRow) * 64 + c1]; \
  }
#define RDB(bv, ni0, cur)                                                      \
  _Pragma("unroll") for (int ni = 0; ni < 2; ++ni) {                           \
    bv[ni][0] = *(const bf16x8*)&Bs[cur][wn >> 1][(((ni0) + ni) * 16 + bRow) * 64 + c0]; \
    bv[ni][1] = *(const bf16x8*)&Bs[cur][wn >> 1][(((ni0) + ni) * 16 + bRow) * 64 + c1]; \
  }
#define PHTOP()                                        \
  asm volatile("" ::: "memory");                       \
  __builtin_amdgcn_s_barrier();                        \
  asm volatile("s_waitcnt lgkmcnt(0)" ::: "memory");   \
  __builtin_amdgcn_s_setprio(1)
#define PHEND()                                        \
  __builtin_amdgcn_s_setprio(0);                       \
  asm volatile("" ::: "memory");                       \
  __builtin_amdgcn_s_barrier()
#define PHENDW()                                       \
  __builtin_amdgcn_s_setprio(0);                       \
  asm volatile("s_waitcnt vmcnt(8)" ::: "memory");     \
  __builtin_amdgcn_s_barrier()
#define MMA16(am0, bv, ni0)                                                    \
  _Pragma("unroll") for (int mi = 0; mi < 4; ++mi)                             \
  _Pragma("unroll") for (int ni = 0; ni < 2; ++ni)                             \
  _Pragma("unroll") for (int kk = 0; kk < 2; ++kk)                             \
    acc[(am0) + mi][(ni0) + ni] = __builtin_amdgcn_mfma_f32_16x16x32_bf16(     \
        a[mi][kk], bv[ni][kk], acc[(am0) + mi][(ni0) + ni], 0, 0, 0);

  f32x4 acc[8][4] = {};
  const int nt = K >> 6;
  const int niter = nt >> 1;

  {
    const int k1 = (nt > 1 ? 1 : 0) << 6;
    SB0(0, 0); SB1(0, 0); SA0(0, 0); SA1(0, 0);
    SB0(1, k1); SB1(1, k1); SA0(1, k1); SA1(1, k1);
  }
  asm volatile("s_waitcnt vmcnt(8)" ::: "memory");
  asm volatile("" ::: "memory");
  __builtin_amdgcn_s_barrier();
  asm volatile("" ::: "memory");

  for (int i = 0; i < niter; ++i) {
    const int k2 = (2 * i + 2 < nt ? 2 * i + 2 : nt - 1) << 6;
    const int k3 = (2 * i + 3 < nt ? 2 * i + 3 : nt - 1) << 6;
    bf16x8 a[4][2], b0[2][2], b1[2][2];

    RDA(0, 0); RDB(b0, 0, 0);
    PHTOP(); MMA16(0, b0, 0); PHEND();
    RDB(b1, 2, 0);
    PHTOP(); MMA16(0, b1, 2); PHEND();
    RDA(4, 0);
    SB0(0, k2); SB1(0, k2);
    PHTOP(); MMA16(4, b1, 2); PHEND();
    SA0(0, k2); SA1(0, k2);
    PHTOP(); MMA16(4, b0, 0); PHENDW();

    RDA(0, 1); RDB(b0, 0, 1);
    PHTOP(); MMA16(0, b0, 0); PHEND();
    RDB(b1, 2, 1);
    PHTOP(); MMA16(0, b1, 2); PHEND();
    RDA(4, 1);
    SB0(1, k3); SB1(1, k3);
    PHTOP(); MMA16(4, b1, 2); PHEND();
    SA0(1, k3); SA1(1, k3);
    PHTOP(); MMA16(4, b0, 0); PHENDW();
  }
#undef SA0
#undef SA1
#undef SB0
#undef SB1
#undef RDA
#undef RDB
#undef PHTOP
#undef PHEND
#undef PHENDW
#undef MMA16

  const int row0 = bm * 256 + wm * 128;
  const int col0 = bn * 256 + wn * 64;
#pragma unroll
  for (int mi = 0; mi < 8; ++mi)
#pragma unroll
    for (int ni = 0; ni < 4; ++ni)
#pragma unroll
      for (int r = 0; r < 4; ++r)
        C[(size_t)(row0 + mi * 16 + lg * 4 + r) * N + (col0 + ni * 16 + lr)] =
            (OutT)acc[mi][ni][r];
}

// ---------------- fused RoPE + RMSNorm (in-place on Q and K regions) -------
__global__ __launch_bounds__(256) void k_rope_norm(__bf16* __restrict__ qkv,
                                                   const float* __restrict__ cosT,
                                                   const float* __restrict__ sinT) {
  const int task = blockIdx.x * 4 + (threadIdx.x >> 6);
  const int l = threadIdx.x & 63;
  const int m = task / 40;          // row in [0, 4096)
  const int h = task - m * 40;      // 0..31 = Q heads, 32..39 = K heads
  const int s = m & (SEQ - 1);
  const bool isQ = h < 32;
  const int col = isQ ? h * 128 : 4096 + (h - 32) * 128;
  __bf16* p = qkv + (size_t)m * QKVN + col + l * 2;
  float e = (float)p[0], o = (float)p[1];
  float c = cosT[s * 64 + l], sn = sinT[s * 64 + l];
  float e2 = e * c - o * sn;
  float o2 = e * sn + o * c;
  float ss = e2 * e2 + o2 * o2;
#pragma unroll
  for (int off = 32; off > 0; off >>= 1) ss += __shfl_xor(ss, off);
  float r = rsqrtf(ss * (1.0f / 128.0f) + 1e-5f);
  if (isQ) r *= 0.08838834764831845f;  // fold 1/sqrt(HEAD_DIM) into Q
  p[0] = (__bf16)(e2 * r);
  p[1] = (__bf16)(o2 * r);
}

// ---------------- V transpose: qkv V region (b,s,g,d) -> vt (b,g,d,s) ------
__global__ __launch_bounds__(256) void k_transpose_v(const __bf16* __restrict__ qkv,
                                                     __bf16* __restrict__ vt) {
  __shared__ __bf16 tile[64][136];  // padded row, no bank conflicts
  const int t = threadIdx.x;
  const int st = blockIdx.x, bg = blockIdx.y;
  const int b = bg >> 3, g = bg & 7;
  const int s0 = st * 64;
#pragma unroll
  for (int p = 0; p < 4; ++p) {
    int row = p * 16 + (t >> 4);
    int co = (t & 15) * 8;
    *(bf16x8*)&tile[row][co] =
        *(const bf16x8*)&qkv[(size_t)(b * SEQ + s0 + row) * QKVN + 5120 + g * 128 + co];
  }
  __syncthreads();
#pragma unroll
  for (int p = 0; p < 4; ++p) {
    int d = p * 32 + (t >> 3);
    int so = (t & 7) * 8;
    bf16x8 v;
#pragma unroll
    for (int j = 0; j < 8; ++j) v[j] = tile[so + j][d];
    *(bf16x8*)&vt[((size_t)bg * 128 + d) * SEQ + s0 + so] = v;
  }
}

// ---------------- causal flash attention (GQA) ------------------------------
// ROUND-16 CHANGE: __launch_bounds__(256, 4) — VGPR_Count was 136, capping
// occupancy at 3 blocks/CU (3 waves/SIMD) while the 40 KB LDS allows 4.
// Flash is TLP-bound (r12: time ~ 1/blocks-per-CU), so the 8-reg squeeze
// (trivially rematerializable) buys 33% more TLP; grid 1024 = 256x4 becomes
// a single fully-resident round. Spill falsification: WRITE_SIZE inflation.
__global__ __launch_bounds__(256, 4) void k_flash(const __bf16* __restrict__ qkv,
                                                  const __bf16* __restrict__ vt,
                                                  __bf16* __restrict__ attno) {
  __shared__ __bf16 Ks[64 * 128];   // [kv][d], swizzled
  __shared__ __bf16 Vs[128 * 64];   // [d][kv], swizzled
  __shared__ __bf16 Ps[4][16 * 64]; // per-wave [q][kv], swizzled
  const int t = threadIdx.x, w = t >> 6, l = t & 63;
  const int lr = l & 15, lg = l >> 4;
  const int bh = blockIdx.y;        // b*32 + h
  const int b = bh >> 5, h = bh & 31, g = h >> 2;
  const int qt0 = blockIdx.x, qt1 = 31 - (int)blockIdx.x;

  const __bf16* kp = qkv + 4096 + (size_t)(b * SEQ + (t >> 4)) * QKVN + g * 128 +
                     (((t & 15) ^ ((t >> 4) & 7)) * 8);
  const __bf16* vp = vt + (size_t)(b * 8 + g) * 128 * SEQ + (size_t)(t >> 3) * SEQ +
                     (((t & 7) ^ ((t >> 3) & 7)) * 8);
  const int wbase = (t & ~63) * 8;
  const int sw = lr & 7;

  for (int pass = 0; pass < 2; ++pass) {
    const int qt = (pass == 0) ? qt0 : qt1;

    const __bf16* Qb = qkv + (size_t)(b * SEQ + qt * 64 + w * 16 + lr) * QKVN + h * 128;
    bf16x8 qf[4];
#pragma unroll
    for (int kk = 0; kk < 4; ++kk) qf[kk] = *(const bf16x8*)&Qb[kk * 32 + lg * 8];

    f32x4 oacc[8] = {};
    float mrow[4], lsum[4];
#pragma unroll
    for (int r = 0; r < 4; ++r) { mrow[r] = -1e30f; lsum[r] = 0.f; }

    for (int kt = 0; kt <= qt; ++kt) {
      const size_t kv0 = (size_t)kt * 64;
#pragma unroll
      for (int i = 0; i < 4; ++i)
        gld_lds16(kp + (kv0 + i * 16) * QKVN, &Ks[i * 2048 + wbase]);
#pragma unroll
      for (int i = 0; i < 4; ++i)
        gld_lds16(vp + (size_t)i * 32 * SEQ + kv0, &Vs[i * 2048 + wbase]);
      __syncthreads();

      // S = Q K^T
      f32x4 sc[4] = {};
      __builtin_amdgcn_s_setprio(1);
#pragma unroll
      for (int kk = 0; kk < 4; ++kk)
#pragma unroll
        for (int n = 0; n < 4; ++n) {
          bf16x8 kf = *(const bf16x8*)&Ks[(n * 16 + lr) * 128 + ((kk * 4 + lg) ^ sw) * 8];
          sc[n] = __builtin_amdgcn_mfma_f32_16x16x32_bf16(qf[kk], kf, sc[n], 0, 0, 0);
        }
      __builtin_amdgcn_s_setprio(0);

      if (kt == qt) {  // diagonal tile: causal mask
#pragma unroll
        for (int n = 0; n < 4; ++n)
#pragma unroll
          for (int r = 0; r < 4; ++r)
            if (n * 16 + lr > w * 16 + lg * 4 + r) sc[n][r] = -1e30f;
      }

      // online softmax with defer-max (T13, THR=8)
      float pml[4];
      float need = -1e30f;
#pragma unroll
      for (int r = 0; r < 4; ++r) {
        pml[r] = fmaxf(fmaxf(sc[0][r], sc[1][r]), fmaxf(sc[2][r], sc[3][r]));
        need = fmaxf(need, pml[r] - mrow[r]);
      }
      if (__all(need <= 8.0f)) {
#pragma unroll
        for (int r = 0; r < 4; ++r) {
          float ps = 0.f;
#pragma unroll
          for (int n = 0; n < 4; ++n) { sc[n][r] = __expf(sc[n][r] - mrow[r]); ps += sc[n][r]; }
#pragma unroll
          for (int off = 8; off > 0; off >>= 1) ps += __shfl_xor(ps, off);
          lsum[r] += ps;
        }
      } else {
#pragma unroll
        for (int r = 0; r < 4; ++r) {
          float pm = pml[r];
#pragma unroll
          for (int off = 8; off > 0; off >>= 1) pm = fmaxf(pm, __shfl_xor(pm, off));
          float mn = fmaxf(mrow[r], pm);
          float corr = __expf(mrow[r] - mn);
          mrow[r] = mn;
          float ps = 0.f;
#pragma unroll
          for (int n = 0; n < 4; ++n) { sc[n][r] = __expf(sc[n][r] - mn); ps += sc[n][r]; }
#pragma unroll
          for (int off = 8; off > 0; off >>= 1) ps += __shfl_xor(ps, off);
          lsum[r] = lsum[r] * corr + ps;
#pragma unroll
          for (int dn = 0; dn < 8; ++dn) oacc[dn][r] *= corr;
        }
      }

      // P -> LDS (swizzled)
#pragma unroll
      for (int n = 0; n < 4; ++n)
#pragma unroll
        for (int r = 0; r < 4; ++r) {
          int row = lg * 4 + r;
          Ps[w][row * 64 + (((n * 2 + (lr >> 3)) ^ (row & 7)) * 8) + (lr & 7)] = (__bf16)sc[n][r];
        }

      // O += P V
      __builtin_amdgcn_s_setprio(1);
#pragma unroll
      for (int ks = 0; ks < 2; ++ks) {
        bf16x8 pf = *(const bf16x8*)&Ps[w][lr * 64 + ((ks * 4 + lg) ^ sw) * 8];
#pragma unroll
        for (int dn = 0; dn < 8; ++dn) {
          bf16x8 vf = *(const bf16x8*)&Vs[(dn * 16 + lr) * 64 + ((ks * 4 + lg) ^ sw) * 8];
          oacc[dn] = __builtin_amdgcn_mfma_f32_16x16x32_bf16(pf, vf, oacc[dn], 0, 0, 0);
        }
      }
      __builtin_amdgcn_s_setprio(0);
      __syncthreads();
    }

    float inv[4];
#pragma unroll
    for (int r = 0; r < 4; ++r) inv[r] = __builtin_amdgcn_rcpf(lsum[r]);
    __bf16* Ob = attno + (size_t)(b * SEQ + qt * 64 + w * 16) * DIMSZ + h * 128;
#pragma unroll
    for (int dn = 0; dn < 8; ++dn)
#pragma unroll
      for (int r = 0; r < 4; ++r)
        Ob[(size_t)(lg * 4 + r) * DIMSZ + dn * 16 + lr] = (__bf16)(oacc[dn][r] * inv[r]);
  }
}

// ---------------- host launcher --------------------------------------------
extern "C" void kernel_launch(void* const* d_in, const int* in_sizes, int n_in,
                              void* d_out, int out_size, void* d_ws, size_t ws_size,
                              hipStream_t stream) {
  const float* x    = (const float*)d_in[0];
  const float* wq   = (const float*)d_in[1];
  const float* wk   = (const float*)d_in[2];
  const float* wv   = (const float*)d_in[3];
  const float* wo   = (const float*)d_in[4];
  const float* cosT = (const float*)d_in[5];
  const float* sinT = (const float*)d_in[6];
  // d_in[7] (mask) implemented as causal; d_in[8] (start_pos) == 0.

  char* ws = (char*)d_ws;
  __bf16* xb    = (__bf16*)(ws);                    // 4096x4096        (32 MiB)
  __bf16* wqkvb = (__bf16*)(ws + 33554432);         // 6144x4096        (48 MiB)
  __bf16* qkvb  = (__bf16*)(ws + 83886080);         // 4096x6144        (48 MiB)
  __bf16* wob   = (__bf16*)(ws + 134217728);        // 4096x4096        (32 MiB)
  __bf16* vt    = (__bf16*)(ws + 167772160);        // 16x128x2048      ( 8 MiB)
  __bf16* attno = (__bf16*)(ws + 176160768);        // 4096x4096        (32 MiB)
  float* out = (float*)d_out;

  // fp32 -> bf16 conversions, single merged launch
  k_cvt5<<<4096, 256, 0, stream>>>(x, wq, wk, wv, wo, xb, wqkvb, wob);

  // QKV projection: 128x256 tiles -> grid (24, 32) = 768 blocks = 3 exact
  // rounds (r14 best: 236 µs)
  k_gemm128x256<<<dim3(24, 32), 512, 0, stream>>>(xb, wqkvb, qkvb, 4096, QKVN, 4096);
  // RoPE + RMSNorm on Q,K (in place), attention scale folded into Q
  k_rope_norm<<<40960, 256, 0, stream>>>(qkvb, cosT, sinT);
  // V -> V^T for contiguous PV operand reads
  k_transpose_v<<<dim3(32, 16), 256, 0, stream>>>(qkvb, vt);
  // causal GQA flash attention (paired q-tiles; now 4 blocks/CU)
  k_flash<<<dim3(16, 64), 256, 0, stream>>>(qkvb, vt, attno);
  // output projection: 256x256 -> grid (16, 16) = 256 blocks = 1 exact round
  k_gemm8p<float><<<dim3(16, 16), 512, 0, stream>>>(attno, wob, out, 4096, DIMSZ, 4096);
}

// Round 17
// 586.414 us; speedup vs baseline: 1.3302x; 1.3302x over previous
//
#include <hip/hip_runtime.h>
#include <hip/hip_bf16.h>
#include <stdint.h>

#define SEQ 2048
#define DIMSZ 4096
#define QKVN 6144   // 4096 Q + 1024 K + 1024 V

typedef __attribute__((ext_vector_type(8))) __bf16 bf16x8;
typedef __attribute__((ext_vector_type(4))) float f32x4;

// async global->LDS, 16B per lane; dest = wave-uniform base + lane*16
static __device__ __forceinline__ void gld_lds16(const void* g, void* l) {
  __builtin_amdgcn_global_load_lds(
      (__attribute__((address_space(1))) void*)(g),
      (__attribute__((address_space(3))) void*)(l), 16, 0, 0);
}

// ---------------- merged fp32 -> bf16 conversion (one launch, 5 segments) --
__global__ __launch_bounds__(256) void k_cvt5(const float* __restrict__ x,
                                              const float* __restrict__ wq,
                                              const float* __restrict__ wk,
                                              const float* __restrict__ wv,
                                              const float* __restrict__ wo,
                                              __bf16* __restrict__ xb,
                                              __bf16* __restrict__ wqkvb,
                                              __bf16* __restrict__ wob) {
  long vid = (long)blockIdx.x * 256 + threadIdx.x;
  const long stride = (long)gridDim.x * 256;
  for (; vid < 7340032L; vid += stride) {
    const float* src; __bf16* dst; long off;
    if (vid < 2097152L)      { src = x;  dst = xb;                off = vid; }
    else if (vid < 4194304L) { src = wq; dst = wqkvb;             off = vid - 2097152L; }
    else if (vid < 4718592L) { src = wk; dst = wqkvb + 16777216L; off = vid - 4194304L; }
    else if (vid < 5242880L) { src = wv; dst = wqkvb + 20971520L; off = vid - 4718592L; }
    else                     { src = wo; dst = wob;               off = vid - 5242880L; }
    const long e = off * 8;
    float4 v0 = *(const float4*)(src + e);
    float4 v1 = *(const float4*)(src + e + 4);
    bf16x8 o;
    o[0] = (__bf16)v0.x; o[1] = (__bf16)v0.y; o[2] = (__bf16)v0.z; o[3] = (__bf16)v0.w;
    o[4] = (__bf16)v1.x; o[5] = (__bf16)v1.y; o[6] = (__bf16)v1.z; o[7] = (__bf16)v1.w;
    *(bf16x8*)(dst + e) = o;
  }
}

// ---------------- GEMM1: C = A*B^T, 128x256 tile, BK=64, triple-buffer -----
// r14 best (236 µs): grid (24,32) = 768 blocks = 3 exact rounds, zero tail.
// Variants falsified: r15 wave-128x96 (250), r13 re-stagger (neutral),
// r11 256x384@(512,4) (spill). This is the best measured GEMM1 structure.
__global__ __launch_bounds__(512) void k_gemm128x256(const __bf16* __restrict__ A,
                                                     const __bf16* __restrict__ B,
                                                     __bf16* __restrict__ C,
                                                     int M, int N, int K) {
  __shared__ __align__(16) __bf16 As[3][128 * 64];  // 48 KB
  __shared__ __align__(16) __bf16 Bs[3][256 * 64];  // 96 KB
  const int t = threadIdx.x;
  const int l = t & 63;
  const int w = t >> 6;        // 0..7
  const int wm = w >> 2;       // 0..1 : rows wm*64..+64
  const int wn = w & 3;        // 0..3 : cols wn*64..+64
  const int lr = l & 15, lg = l >> 4;
  const int sw = lr & 7;       // read-side chunk XOR
  const int bm = blockIdx.y, bn = blockIdx.x;

  const int srow = t >> 3;
  const int scol = ((t & 7) ^ (srow & 7)) << 3;
  const __bf16* pa0 = A + (size_t)(bm * 128 +   0 + srow) * K + scol;
  const __bf16* pa1 = A + (size_t)(bm * 128 +  64 + srow) * K + scol;
  const __bf16* pb0 = B + (size_t)(bn * 256 +   0 + srow) * K + scol;
  const __bf16* pb1 = B + (size_t)(bn * 256 +  64 + srow) * K + scol;
  const __bf16* pb2 = B + (size_t)(bn * 256 + 128 + srow) * K + scol;
  const __bf16* pb3 = B + (size_t)(bn * 256 + 192 + srow) * K + scol;
  const int ldst = t * 8;

#define SA(buf, kc) { gld_lds16(pa0 + (kc), &As[buf][ldst]);        \
                      gld_lds16(pa1 + (kc), &As[buf][4096 + ldst]); }
#define SB(buf, kc) { gld_lds16(pb0 + (kc), &Bs[buf][ldst]);        \
                      gld_lds16(pb1 + (kc), &Bs[buf][4096 + ldst]); \
                      gld_lds16(pb2 + (kc), &Bs[buf][8192 + ldst]); \
                      gld_lds16(pb3 + (kc), &Bs[buf][12288 + ldst]); }

  const int c0 = ((lg ^ sw) * 8);
  const int c1 = (((lg ^ sw) ^ 4) * 8);
  const int aBase = wm * 4096 + lr * 64;
  const int bBase = wn * 4096 + lr * 64;

#define PHTOP()                                        \
  asm volatile("" ::: "memory");                       \
  __builtin_amdgcn_s_barrier();                        \
  asm volatile("s_waitcnt lgkmcnt(0)" ::: "memory");   \
  __builtin_amdgcn_s_setprio(1)
#define PHEND()                                        \
  __builtin_amdgcn_s_setprio(0);                       \
  asm volatile("" ::: "memory");                       \
  __builtin_amdgcn_s_barrier()
#define PHENDW()                                       \
  __builtin_amdgcn_s_setprio(0);                       \
  asm volatile("s_waitcnt vmcnt(6)" ::: "memory");     \
  __builtin_amdgcn_s_barrier()

  f32x4 acc[4][4] = {};
  const int nt = K >> 6;

  SA(0, 0); SB(0, 0);
  SA(1, 64); SB(1, 64);
  asm volatile("s_waitcnt vmcnt(6)" ::: "memory");
  asm volatile("" ::: "memory");
  __builtin_amdgcn_s_barrier();
  asm volatile("" ::: "memory");

  int bu = 0, bu2 = 2;
  for (int U = 0; U < nt; ++U) {
    const int kc = (U + 2 < nt ? U + 2 : nt - 1) << 6;
    bf16x8 a[4][2], b[2][2];

    // ---- ph0: a(all) x b01; stage A(U+2) ----
#pragma unroll
    for (int mi = 0; mi < 4; ++mi) {
      a[mi][0] = *(const bf16x8*)&As[bu][aBase + mi * 1024 + c0];
      a[mi][1] = *(const bf16x8*)&As[bu][aBase + mi * 1024 + c1];
    }
#pragma unroll
    for (int ni = 0; ni < 2; ++ni) {
      b[ni][0] = *(const bf16x8*)&Bs[bu][bBase + ni * 1024 + c0];
      b[ni][1] = *(const bf16x8*)&Bs[bu][bBase + ni * 1024 + c1];
    }
    SA(bu2, kc);
    PHTOP();
#pragma unroll
    for (int mi = 0; mi < 4; ++mi)
#pragma unroll
      for (int ni = 0; ni < 2; ++ni)
#pragma unroll
        for (int kk = 0; kk < 2; ++kk)
          acc[mi][ni] = __builtin_amdgcn_mfma_f32_16x16x32_bf16(a[mi][kk], b[ni][kk], acc[mi][ni], 0, 0, 0);
    PHEND();

    // ---- ph1: a(all) x b23; stage B(U+2); counted vmcnt(6) ----
#pragma unroll
    for (int ni = 0; ni < 2; ++ni) {
      b[ni][0] = *(const bf16x8*)&Bs[bu][bBase + (ni + 2) * 1024 + c0];
      b[ni][1] = *(const bf16x8*)&Bs[bu][bBase + (ni + 2) * 1024 + c1];
    }
    SB(bu2, kc);
    PHTOP();
#pragma unroll
    for (int mi = 0; mi < 4; ++mi)
#pragma unroll
      for (int ni = 0; ni < 2; ++ni)
#pragma unroll
        for (int kk = 0; kk < 2; ++kk)
          acc[mi][ni + 2] = __builtin_amdgcn_mfma_f32_16x16x32_bf16(a[mi][kk], b[ni][kk], acc[mi][ni + 2], 0, 0, 0);
    PHENDW();

    bu = (bu == 2) ? 0 : bu + 1;
    bu2 = (bu2 == 2) ? 0 : bu2 + 1;
  }
#undef SA
#undef SB
#undef PHTOP
#undef PHEND
#undef PHENDW

  const int row0 = bm * 128 + wm * 64;
  const int col0 = bn * 256 + wn * 64;
#pragma unroll
  for (int mi = 0; mi < 4; ++mi)
#pragma unroll
    for (int ni = 0; ni < 4; ++ni)
#pragma unroll
      for (int r = 0; r < 4; ++r)
        C[(size_t)(row0 + mi * 16 + lg * 4 + r) * N + (col0 + ni * 16 + lr)] =
            (__bf16)acc[mi][ni][r];
}

// ---------------- GEMM2: r13 8-phase 256x256 kernel (tail-free) ------------
template <typename OutT>
__global__ __launch_bounds__(512) void k_gemm8p(const __bf16* __restrict__ A,
                                                const __bf16* __restrict__ B,
                                                OutT* __restrict__ C,
                                                int M, int N, int K) {
  __shared__ __align__(16) __bf16 As[2][2][128 * 64];  // 64 KiB
  __shared__ __align__(16) __bf16 Bs[2][2][128 * 64];  // 64 KiB
  const int t = threadIdx.x;
  const int l = t & 63;
  const int w = t >> 6;
  const int wm = w >> 2;
  const int wn = w & 3;
  const int lr = l & 15, lg = l >> 4;
  const int sw = lr & 7;
  const int bm = blockIdx.y, bn = blockIdx.x;

  const int srow = t >> 3;
  const int scol = ((t & 7) ^ (srow & 7)) << 3;
  const __bf16* pa0 = A + (size_t)(bm * 256 +   0 + srow) * K + scol;
  const __bf16* pa1 = A + (size_t)(bm * 256 +  64 + srow) * K + scol;
  const __bf16* pa2 = A + (size_t)(bm * 256 + 128 + srow) * K + scol;
  const __bf16* pa3 = A + (size_t)(bm * 256 + 192 + srow) * K + scol;
  const __bf16* pb0 = B + (size_t)(bn * 256 +   0 + srow) * K + scol;
  const __bf16* pb1 = B + (size_t)(bn * 256 +  64 + srow) * K + scol;
  const __bf16* pb2 = B + (size_t)(bn * 256 + 128 + srow) * K + scol;
  const __bf16* pb3 = B + (size_t)(bn * 256 + 192 + srow) * K + scol;
  const int ldst = t * 8;

#define SA0(buf, kc) { gld_lds16(pa0 + (kc), &As[buf][0][ldst]); gld_lds16(pa1 + (kc), &As[buf][0][4096 + ldst]); }
#define SA1(buf, kc) { gld_lds16(pa2 + (kc), &As[buf][1][ldst]); gld_lds16(pa3 + (kc), &As[buf][1][4096 + ldst]); }
#define SB0(buf, kc) { gld_lds16(pb0 + (kc), &Bs[buf][0][ldst]); gld_lds16(pb1 + (kc), &Bs[buf][0][4096 + ldst]); }
#define SB1(buf, kc) { gld_lds16(pb2 + (kc), &Bs[buf][1][ldst]); gld_lds16(pb3 + (kc), &Bs[buf][1][4096 + ldst]); }

  const int c0 = ((lg ^ sw) * 8);
  const int c1 = (((lg ^ sw) ^ 4) * 8);
  const int aRow = lr;
  const int bRow = (wn & 1) * 64 + lr;

#define RDA(mi0, cur)                                                          \
  _Pragma("unroll") for (int mi = 0; mi < 4; ++mi) {                           \
    a[mi][0] = *(const bf16x8*)&As[cur][wm][(((mi0) + mi) * 16 + aRow) * 64 + c0]; \
    a[mi][1] = *(const bf16x8*)&As[cur][wm][(((mi0) + mi) * 16 + aRow) * 64 + c1]; \
  }
#define RDB(bv, ni0, cur)                                                      \
  _Pragma("unroll") for (int ni = 0; ni < 2; ++ni) {                           \
    bv[ni][0] = *(const bf16x8*)&Bs[cur][wn >> 1][(((ni0) + ni) * 16 + bRow) * 64 + c0]; \
    bv[ni][1] = *(const bf16x8*)&Bs[cur][wn >> 1][(((ni0) + ni) * 16 + bRow) * 64 + c1]; \
  }
#define PHTOP()                                        \
  asm volatile("" ::: "memory");                       \
  __builtin_amdgcn_s_barrier();                        \
  asm volatile("s_waitcnt lgkmcnt(0)" ::: "memory");   \
  __builtin_amdgcn_s_setprio(1)
#define PHEND()                                        \
  __builtin_amdgcn_s_setprio(0);                       \
  asm volatile("" ::: "memory");                       \
  __builtin_amdgcn_s_barrier()
#define PHENDW()                                       \
  __builtin_amdgcn_s_setprio(0);                       \
  asm volatile("s_waitcnt vmcnt(8)" ::: "memory");     \
  __builtin_amdgcn_s_barrier()
#define MMA16(am0, bv, ni0)                                                    \
  _Pragma("unroll") for (int mi = 0; mi < 4; ++mi)                             \
  _Pragma("unroll") for (int ni = 0; ni < 2; ++ni)                             \
  _Pragma("unroll") for (int kk = 0; kk < 2; ++kk)                             \
    acc[(am0) + mi][(ni0) + ni] = __builtin_amdgcn_mfma_f32_16x16x32_bf16(     \
        a[mi][kk], bv[ni][kk], acc[(am0) + mi][(ni0) + ni], 0, 0, 0);

  f32x4 acc[8][4] = {};
  const int nt = K >> 6;
  const int niter = nt >> 1;

  {
    const int k1 = (nt > 1 ? 1 : 0) << 6;
    SB0(0, 0); SB1(0, 0); SA0(0, 0); SA1(0, 0);
    SB0(1, k1); SB1(1, k1); SA0(1, k1); SA1(1, k1);
  }
  asm volatile("s_waitcnt vmcnt(8)" ::: "memory");
  asm volatile("" ::: "memory");
  __builtin_amdgcn_s_barrier();
  asm volatile("" ::: "memory");

  for (int i = 0; i < niter; ++i) {
    const int k2 = (2 * i + 2 < nt ? 2 * i + 2 : nt - 1) << 6;
    const int k3 = (2 * i + 3 < nt ? 2 * i + 3 : nt - 1) << 6;
    bf16x8 a[4][2], b0[2][2], b1[2][2];

    RDA(0, 0); RDB(b0, 0, 0);
    PHTOP(); MMA16(0, b0, 0); PHEND();
    RDB(b1, 2, 0);
    PHTOP(); MMA16(0, b1, 2); PHEND();
    RDA(4, 0);
    SB0(0, k2); SB1(0, k2);
    PHTOP(); MMA16(4, b1, 2); PHEND();
    SA0(0, k2); SA1(0, k2);
    PHTOP(); MMA16(4, b0, 0); PHENDW();

    RDA(0, 1); RDB(b0, 0, 1);
    PHTOP(); MMA16(0, b0, 0); PHEND();
    RDB(b1, 2, 1);
    PHTOP(); MMA16(0, b1, 2); PHEND();
    RDA(4, 1);
    SB0(1, k3); SB1(1, k3);
    PHTOP(); MMA16(4, b1, 2); PHEND();
    SA0(1, k3); SA1(1, k3);
    PHTOP(); MMA16(4, b0, 0); PHENDW();
  }
#undef SA0
#undef SA1
#undef SB0
#undef SB1
#undef RDA
#undef RDB
#undef PHTOP
#undef PHEND
#undef PHENDW
#undef MMA16

  const int row0 = bm * 256 + wm * 128;
  const int col0 = bn * 256 + wn * 64;
#pragma unroll
  for (int mi = 0; mi < 8; ++mi)
#pragma unroll
    for (int ni = 0; ni < 4; ++ni)
#pragma unroll
      for (int r = 0; r < 4; ++r)
        C[(size_t)(row0 + mi * 16 + lg * 4 + r) * N + (col0 + ni * 16 + lr)] =
            (OutT)acc[mi][ni][r];
}

// ---------------- fused RoPE + RMSNorm (in-place on Q and K regions) -------
__global__ __launch_bounds__(256) void k_rope_norm(__bf16* __restrict__ qkv,
                                                   const float* __restrict__ cosT,
                                                   const float* __restrict__ sinT) {
  const int task = blockIdx.x * 4 + (threadIdx.x >> 6);
  const int l = threadIdx.x & 63;
  const int m = task / 40;          // row in [0, 4096)
  const int h = task - m * 40;      // 0..31 = Q heads, 32..39 = K heads
  const int s = m & (SEQ - 1);
  const bool isQ = h < 32;
  const int col = isQ ? h * 128 : 4096 + (h - 32) * 128;
  __bf16* p = qkv + (size_t)m * QKVN + col + l * 2;
  float e = (float)p[0], o = (float)p[1];
  float c = cosT[s * 64 + l], sn = sinT[s * 64 + l];
  float e2 = e * c - o * sn;
  float o2 = e * sn + o * c;
  float ss = e2 * e2 + o2 * o2;
#pragma unroll
  for (int off = 32; off > 0; off >>= 1) ss += __shfl_xor(ss, off);
  float r = rsqrtf(ss * (1.0f / 128.0f) + 1e-5f);
  if (isQ) r *= 0.08838834764831845f;  // fold 1/sqrt(HEAD_DIM) into Q
  p[0] = (__bf16)(e2 * r);
  p[1] = (__bf16)(o2 * r);
}

// ---------------- V transpose: qkv V region (b,s,g,d) -> vt (b,g,d,s) ------
__global__ __launch_bounds__(256) void k_transpose_v(const __bf16* __restrict__ qkv,
                                                     __bf16* __restrict__ vt) {
  __shared__ __bf16 tile[64][136];  // padded row, no bank conflicts
  const int t = threadIdx.x;
  const int st = blockIdx.x, bg = blockIdx.y;
  const int b = bg >> 3, g = bg & 7;
  const int s0 = st * 64;
#pragma unroll
  for (int p = 0; p < 4; ++p) {
    int row = p * 16 + (t >> 4);
    int co = (t & 15) * 8;
    *(bf16x8*)&tile[row][co] =
        *(const bf16x8*)&qkv[(size_t)(b * SEQ + s0 + row) * QKVN + 5120 + g * 128 + co];
  }
  __syncthreads();
#pragma unroll
  for (int p = 0; p < 4; ++p) {
    int d = p * 32 + (t >> 3);
    int so = (t & 7) * 8;
    bf16x8 v;
#pragma unroll
    for (int j = 0; j < 8; ++j) v[j] = tile[so + j][d];
    *(bf16x8*)&vt[((size_t)bg * 128 + d) * SEQ + s0 + so] = v;
  }
}

// ---------------- causal flash attention (GQA) — r9/r14 version ------------
// r16's launch_bounds(256,4) REVERTED: compiler spilled (VGPR 64 + 842 MB
// FETCH = scratch traffic, flash 120->357 µs). Default bounds: 136 VGPR,
// 3 blocks/CU, no spill — the measured-best flash (~120 µs).
__global__ __launch_bounds__(256) void k_flash(const __bf16* __restrict__ qkv,
                                               const __bf16* __restrict__ vt,
                                               __bf16* __restrict__ attno) {
  __shared__ __bf16 Ks[64 * 128];   // [kv][d], swizzled
  __shared__ __bf16 Vs[128 * 64];   // [d][kv], swizzled
  __shared__ __bf16 Ps[4][16 * 64]; // per-wave [q][kv], swizzled
  const int t = threadIdx.x, w = t >> 6, l = t & 63;
  const int lr = l & 15, lg = l >> 4;
  const int bh = blockIdx.y;        // b*32 + h
  const int b = bh >> 5, h = bh & 31, g = h >> 2;
  const int qt0 = blockIdx.x, qt1 = 31 - (int)blockIdx.x;

  const __bf16* kp = qkv + 4096 + (size_t)(b * SEQ + (t >> 4)) * QKVN + g * 128 +
                     (((t & 15) ^ ((t >> 4) & 7)) * 8);
  const __bf16* vp = vt + (size_t)(b * 8 + g) * 128 * SEQ + (size_t)(t >> 3) * SEQ +
                     (((t & 7) ^ ((t >> 3) & 7)) * 8);
  const int wbase = (t & ~63) * 8;
  const int sw = lr & 7;

  for (int pass = 0; pass < 2; ++pass) {
    const int qt = (pass == 0) ? qt0 : qt1;

    const __bf16* Qb = qkv + (size_t)(b * SEQ + qt * 64 + w * 16 + lr) * QKVN + h * 128;
    bf16x8 qf[4];
#pragma unroll
    for (int kk = 0; kk < 4; ++kk) qf[kk] = *(const bf16x8*)&Qb[kk * 32 + lg * 8];

    f32x4 oacc[8] = {};
    float mrow[4], lsum[4];
#pragma unroll
    for (int r = 0; r < 4; ++r) { mrow[r] = -1e30f; lsum[r] = 0.f; }

    for (int kt = 0; kt <= qt; ++kt) {
      const size_t kv0 = (size_t)kt * 64;
#pragma unroll
      for (int i = 0; i < 4; ++i)
        gld_lds16(kp + (kv0 + i * 16) * QKVN, &Ks[i * 2048 + wbase]);
#pragma unroll
      for (int i = 0; i < 4; ++i)
        gld_lds16(vp + (size_t)i * 32 * SEQ + kv0, &Vs[i * 2048 + wbase]);
      __syncthreads();

      // S = Q K^T
      f32x4 sc[4] = {};
      __builtin_amdgcn_s_setprio(1);
#pragma unroll
      for (int kk = 0; kk < 4; ++kk)
#pragma unroll
        for (int n = 0; n < 4; ++n) {
          bf16x8 kf = *(const bf16x8*)&Ks[(n * 16 + lr) * 128 + ((kk * 4 + lg) ^ sw) * 8];
          sc[n] = __builtin_amdgcn_mfma_f32_16x16x32_bf16(qf[kk], kf, sc[n], 0, 0, 0);
        }
      __builtin_amdgcn_s_setprio(0);

      if (kt == qt) {  // diagonal tile: causal mask
#pragma unroll
        for (int n = 0; n < 4; ++n)
#pragma unroll
          for (int r = 0; r < 4; ++r)
            if (n * 16 + lr > w * 16 + lg * 4 + r) sc[n][r] = -1e30f;
      }

      // online softmax with defer-max (T13, THR=8)
      float pml[4];
      float need = -1e30f;
#pragma unroll
      for (int r = 0; r < 4; ++r) {
        pml[r] = fmaxf(fmaxf(sc[0][r], sc[1][r]), fmaxf(sc[2][r], sc[3][r]));
        need = fmaxf(need, pml[r] - mrow[r]);
      }
      if (__all(need <= 8.0f)) {
#pragma unroll
        for (int r = 0; r < 4; ++r) {
          float ps = 0.f;
#pragma unroll
          for (int n = 0; n < 4; ++n) { sc[n][r] = __expf(sc[n][r] - mrow[r]); ps += sc[n][r]; }
#pragma unroll
          for (int off = 8; off > 0; off >>= 1) ps += __shfl_xor(ps, off);
          lsum[r] += ps;
        }
      } else {
#pragma unroll
        for (int r = 0; r < 4; ++r) {
          float pm = pml[r];
#pragma unroll
          for (int off = 8; off > 0; off >>= 1) pm = fmaxf(pm, __shfl_xor(pm, off));
          float mn = fmaxf(mrow[r], pm);
          float corr = __expf(mrow[r] - mn);
          mrow[r] = mn;
          float ps = 0.f;
#pragma unroll
          for (int n = 0; n < 4; ++n) { sc[n][r] = __expf(sc[n][r] - mn); ps += sc[n][r]; }
#pragma unroll
          for (int off = 8; off > 0; off >>= 1) ps += __shfl_xor(ps, off);
          lsum[r] = lsum[r] * corr + ps;
#pragma unroll
          for (int dn = 0; dn < 8; ++dn) oacc[dn][r] *= corr;
        }
      }

      // P -> LDS (swizzled)
#pragma unroll
      for (int n = 0; n < 4; ++n)
#pragma unroll
        for (int r = 0; r < 4; ++r) {
          int row = lg * 4 + r;
          Ps[w][row * 64 + (((n * 2 + (lr >> 3)) ^ (row & 7)) * 8) + (lr & 7)] = (__bf16)sc[n][r];
        }

      // O += P V
      __builtin_amdgcn_s_setprio(1);
#pragma unroll
      for (int ks = 0; ks < 2; ++ks) {
        bf16x8 pf = *(const bf16x8*)&Ps[w][lr * 64 + ((ks * 4 + lg) ^ sw) * 8];
#pragma unroll
        for (int dn = 0; dn < 8; ++dn) {
          bf16x8 vf = *(const bf16x8*)&Vs[(dn * 16 + lr) * 64 + ((ks * 4 + lg) ^ sw) * 8];
          oacc[dn] = __builtin_amdgcn_mfma_f32_16x16x32_bf16(pf, vf, oacc[dn], 0, 0, 0);
        }
      }
      __builtin_amdgcn_s_setprio(0);
      __syncthreads();
    }

    float inv[4];
#pragma unroll
    for (int r = 0; r < 4; ++r) inv[r] = __builtin_amdgcn_rcpf(lsum[r]);
    __bf16* Ob = attno + (size_t)(b * SEQ + qt * 64 + w * 16) * DIMSZ + h * 128;
#pragma unroll
    for (int dn = 0; dn < 8; ++dn)
#pragma unroll
      for (int r = 0; r < 4; ++r)
        Ob[(size_t)(lg * 4 + r) * DIMSZ + dn * 16 + lr] = (__bf16)(oacc[dn][r] * inv[r]);
  }
}

// ---------------- host launcher --------------------------------------------
extern "C" void kernel_launch(void* const* d_in, const int* in_sizes, int n_in,
                              void* d_out, int out_size, void* d_ws, size_t ws_size,
                              hipStream_t stream) {
  const float* x    = (const float*)d_in[0];
  const float* wq   = (const float*)d_in[1];
  const float* wk   = (const float*)d_in[2];
  const float* wv   = (const float*)d_in[3];
  const float* wo   = (const float*)d_in[4];
  const float* cosT = (const float*)d_in[5];
  const float* sinT = (const float*)d_in[6];
  // d_in[7] (mask) implemented as causal; d_in[8] (start_pos) == 0.

  char* ws = (char*)d_ws;
  __bf16* xb    = (__bf16*)(ws);                    // 4096x4096        (32 MiB)
  __bf16* wqkvb = (__bf16*)(ws + 33554432);         // 6144x4096        (48 MiB)
  __bf16* qkvb  = (__bf16*)(ws + 83886080);         // 4096x6144        (48 MiB)
  __bf16* wob   = (__bf16*)(ws + 134217728);        // 4096x4096        (32 MiB)
  __bf16* vt    = (__bf16*)(ws + 167772160);        // 16x128x2048      ( 8 MiB)
  __bf16* attno = (__bf16*)(ws + 176160768);        // 4096x4096        (32 MiB)
  float* out = (float*)d_out;

  // fp32 -> bf16 conversions, single merged launch
  k_cvt5<<<4096, 256, 0, stream>>>(x, wq, wk, wv, wo, xb, wqkvb, wob);

  // QKV projection: 128x256 tiles -> grid (24, 32) = 768 blocks = 3 exact
  // rounds (r14 best: 236 µs)
  k_gemm128x256<<<dim3(24, 32), 512, 0, stream>>>(xb, wqkvb, qkvb, 4096, QKVN, 4096);
  // RoPE + RMSNorm on Q,K (in place), attention scale folded into Q
  k_rope_norm<<<40960, 256, 0, stream>>>(qkvb, cosT, sinT);
  // V -> V^T for contiguous PV operand reads
  k_transpose_v<<<dim3(32, 16), 256, 0, stream>>>(qkvb, vt);
  // causal GQA flash attention (paired q-tiles; default bounds, no spill)
  k_flash<<<dim3(16, 64), 256, 0, stream>>>(qkvb, vt, attno);
  // output projection: 256x256 -> grid (16, 16) = 256 blocks = 1 exact round
  k_gemm8p<float><<<dim3(16, 16), 512, 0, stream>>>(attno, wob, out, 4096, DIMSZ, 4096);
}